// Round 1
// baseline (237.041 us; speedup 1.0000x reference)
//
#include <hip/hip_runtime.h>
#include <hip/hip_bf16.h>

// Embedding gather: out[token] = W_E[tokens[token]]
// tokens: int32[8*4096] = 32768, W_E: float32[50257*768], out: float32[32768*768]
// One 64-lane wave per token; each lane copies 3 float4 (192 float4 = 768 floats).

#define D_MODEL4 192  // 768 / 4

__global__ __launch_bounds__(256) void embed_gather_kernel(
    const int* __restrict__ tokens,
    const float4* __restrict__ W_E,
    float4* __restrict__ out,
    int n_tokens)
{
    const int gtid = blockIdx.x * blockDim.x + threadIdx.x;
    const int wave = gtid >> 6;          // one wave per token
    const int lane = threadIdx.x & 63;
    if (wave >= n_tokens) return;

    const int tok = tokens[wave];        // same addr across wave -> broadcast
    const float4* __restrict__ src = W_E + (size_t)tok * D_MODEL4;
    float4* __restrict__ dst = out + (size_t)wave * D_MODEL4;

    // 192 float4 per row, 64 lanes -> 3 iterations, fully coalesced 16B/lane
    #pragma unroll
    for (int i = 0; i < 3; ++i) {
        const int idx = lane + i * 64;
        dst[idx] = src[idx];
    }
}

extern "C" void kernel_launch(void* const* d_in, const int* in_sizes, int n_in,
                              void* d_out, int out_size, void* d_ws, size_t ws_size,
                              hipStream_t stream)
{
    const int*   tokens = (const int*)d_in[0];
    const float* W_E    = (const float*)d_in[1];
    float*       out    = (float*)d_out;

    const int n_tokens = in_sizes[0];            // 8 * 4096 = 32768

    // 4 waves (= 4 tokens) per 256-thread block
    const int blocks = (n_tokens + 3) / 4;
    embed_gather_kernel<<<blocks, 256, 0, stream>>>(
        tokens, (const float4*)W_E, (float4*)out, n_tokens);
}

// Round 3
// 236.593 us; speedup vs baseline: 1.0019x; 1.0019x over previous
//
#include <hip/hip_runtime.h>
#include <hip/hip_bf16.h>

// Embedding gather: out[b,s,:] = W_E[tokens[b,s],:]
// tokens: int32[32768], W_E: float32[50257,768], out: float32[32768,768]
//
// One 64-lane wave per 4 tokens. Each lane holds 12 float4 in flight
// (4 rows x 3 float4/lane) before storing -> 4x the memory-level
// parallelism of the wave-per-token version. Stores are nontemporal so
// the 100 MB output stream doesn't evict W_E (154 MB) from the 256 MB
// Infinity Cache (W_E + out = 255 MB: regular stores guarantee LLC
// thrash; nt stores keep W_E resident across graph replays).
//
// NOTE: __builtin_nontemporal_store requires a native clang vector type,
// not HIP's float4 class -> use ext_vector_type(4).

typedef float v4f __attribute__((ext_vector_type(4)));

#define ROW4 192  // 768 floats / 4 = float4 per embedding row

__global__ __launch_bounds__(256) void embed_gather_kernel(
    const int* __restrict__ tokens,
    const v4f* __restrict__ W_E,
    v4f* __restrict__ out,
    int n_tokens)
{
    const int gtid = blockIdx.x * blockDim.x + threadIdx.x;
    const int wave = gtid >> 6;
    const int lane = threadIdx.x & 63;
    const int tok_base = wave * 4;
    if (tok_base >= n_tokens) return;

    if (tok_base + 4 <= n_tokens) {
        // Fast path: 4 tokens per wave, fully unrolled.
        const int4 t4 = *(const int4*)(tokens + tok_base);

        const v4f* __restrict__ s0 = W_E + (size_t)t4.x * ROW4;
        const v4f* __restrict__ s1 = W_E + (size_t)t4.y * ROW4;
        const v4f* __restrict__ s2 = W_E + (size_t)t4.z * ROW4;
        const v4f* __restrict__ s3 = W_E + (size_t)t4.w * ROW4;
        v4f* __restrict__ d = out + (size_t)tok_base * ROW4;

        v4f r[12];
        #pragma unroll
        for (int i = 0; i < 3; ++i) {
            const int idx = lane + i * 64;
            r[i]     = s0[idx];
            r[3 + i] = s1[idx];
            r[6 + i] = s2[idx];
            r[9 + i] = s3[idx];
        }
        #pragma unroll
        for (int i = 0; i < 3; ++i) {
            const int idx = lane + i * 64;
            __builtin_nontemporal_store(r[i],     d + idx);
            __builtin_nontemporal_store(r[3 + i], d + ROW4     + idx);
            __builtin_nontemporal_store(r[6 + i], d + 2 * ROW4 + idx);
            __builtin_nontemporal_store(r[9 + i], d + 3 * ROW4 + idx);
        }
    } else {
        // Tail: per-token copy (not hit for n_tokens % 4 == 0).
        for (int t = tok_base; t < n_tokens; ++t) {
            const int tok = tokens[t];
            const v4f* __restrict__ src = W_E + (size_t)tok * ROW4;
            v4f* __restrict__ dst = out + (size_t)t * ROW4;
            #pragma unroll
            for (int i = 0; i < 3; ++i) {
                const int idx = lane + i * 64;
                __builtin_nontemporal_store(src[idx], dst + idx);
            }
        }
    }
}

extern "C" void kernel_launch(void* const* d_in, const int* in_sizes, int n_in,
                              void* d_out, int out_size, void* d_ws, size_t ws_size,
                              hipStream_t stream)
{
    const int* tokens = (const int*)d_in[0];
    const v4f* W_E    = (const v4f*)d_in[1];
    v4f*       out    = (v4f*)d_out;

    const int n_tokens = in_sizes[0];  // 8 * 4096 = 32768

    // 4 tokens per wave, 4 waves per 256-thread block -> 16 tokens/block.
    const int n_waves = (n_tokens + 3) / 4;
    const int blocks  = (n_waves + 3) / 4;
    embed_gather_kernel<<<blocks, 256, 0, stream>>>(
        tokens, W_E, out, n_tokens);
}